// Round 13
// baseline (817.971 us; speedup 1.0000x reference)
//
#include <hip/hip_runtime.h>
#include <cstdint>
#include <cmath>

#define DIM 384
#define HEADS 12
#define TOKENS 100352   // 32*56*56
#define HW_ 3136        // 56*56
#define NWIN 2048       // 32*8*8

typedef __attribute__((ext_vector_type(8))) short short8;
typedef __attribute__((ext_vector_type(4))) short short4v;
typedef __attribute__((ext_vector_type(2))) short short2v;
typedef __attribute__((ext_vector_type(4))) float f32x4;

#define AS1 __attribute__((address_space(1)))
#define AS3 __attribute__((address_space(3)))

__device__ __forceinline__ short f2b(float f){
  unsigned u = __builtin_bit_cast(unsigned, f);
  u += 0x7FFFu + ((u >> 16) & 1u);
  return (short)(u >> 16);
}
__device__ __forceinline__ float b2f(short h){
  unsigned u = ((unsigned)(unsigned short)h) << 16;
  return __builtin_bit_cast(float, u);
}

__device__ __forceinline__ void gload_lds16(const short* g, short* l){
  __builtin_amdgcn_global_load_lds((AS1 void*)(g), (AS3 void*)(l), 16, 0, 0);
}

// bijective XCD swizzle for any nwg (m204 variant)
__device__ __forceinline__ int bij_swz(int orig, int nwg){
  int q = nwg >> 3, r = nwg & 7;
  int x = orig & 7, w = orig >> 3;
  return (x < r ? x*(q+1) : r*(q+1) + (x-r)*q) + w;
}

// exact GELU via A&S 7.1.26 rational erf (|eps| <= 1.5e-7)
__device__ __forceinline__ float gelu_f(float v){
  float z  = v * 0.70710678118654752f;
  float az = fabsf(z);
  float t  = __builtin_amdgcn_rcpf(1.f + 0.3275911f*az);
  float poly = t*(0.254829592f + t*(-0.284496736f + t*(1.421413741f +
               t*(-1.453152027f + t*1.061405429f))));
  float e  = __expf(-z*z);
  float er = copysignf(1.f - poly*e, z);
  return 0.5f * v * (1.f + er);
}

// ---------------- all 4 weight tensors f32 -> bf16, one launch ----------------
__global__ __launch_bounds__(256) void k_cvt4(
    const float* __restrict__ s0, const float* __restrict__ s1,
    const float* __restrict__ s2, const float* __restrict__ s3,
    short* __restrict__ d0, short* __restrict__ d1,
    short* __restrict__ d2, short* __restrict__ d3)
{
  int i = blockIdx.x*256 + threadIdx.x;
  if (i < 442368) d0[i] = f2b(s0[i]);
  if (i < 147456) d1[i] = f2b(s1[i]);
  if (i < 393216){ d2[i] = f2b(s2[i]); d3[i] = f2b(s3[i]); }
}

// ---------------- LN1 + NCHW->token transpose (single global read) --------
__global__ __launch_bounds__(256) void k_ln1(const float* __restrict__ x,
    const float* __restrict__ gam, const float* __restrict__ bet,
    short* __restrict__ ln1, short* __restrict__ xr)
{
  __shared__ float red0[256];
  __shared__ float red1[256];
  __shared__ float mus[64], rss[64];
  __shared__ short xfull[64*388];
  int t = threadIdx.x;
  int blk = blockIdx.x;
  int b = blk / 49;
  int hw0 = (blk % 49) * 64;
  int p = t & 63, cq = t >> 6;
  const float* xb = x + (long)b*DIM*HW_ + hw0 + p;
  float s = 0.f, sq = 0.f;
  for (int i = 0; i < 96; i++){
    int c = i*4 + cq;
    float v = xb[(long)c*HW_];
    s += v; sq += v*v;
    xfull[p*388 + c] = f2b(v);
  }
  red0[t] = s; red1[t] = sq;
  __syncthreads();
  if (t < 64){
    float ts = red0[t] + red0[t+64] + red0[t+128] + red0[t+192];
    float tq = red1[t] + red1[t+64] + red1[t+128] + red1[t+192];
    float mu = ts * (1.f/DIM);
    float var = tq * (1.f/DIM) - mu*mu;
    mus[t] = mu;
    rss[t] = rsqrtf(var + 1e-5f);
  }
  __syncthreads();
  int p2 = t >> 2, q4 = t & 3;
  float mu = mus[p2], rs = rss[p2];
  int hwp2 = hw0 + p2;
  int h2 = hwp2 / 56, w2 = hwp2 % 56;
  int wt2 = ((b*8 + h2/7)*8 + w2/7)*49 + (h2%7)*7 + (w2%7);
  long lnbase = (long)wt2*DIM;
  long xrbase = (long)(b*HW_ + hwp2)*DIM;
  #pragma unroll
  for (int cc0 = 0; cc0 < DIM; cc0 += 32){
    short8 xv = *(const short8*)(xfull + p2*388 + cc0 + q4*8);
    short8 lv;
    #pragma unroll
    for (int u = 0; u < 8; u++){
      int c = cc0 + q4*8 + u;
      float v = b2f(xv[u]);
      lv[u] = f2b((v - mu)*rs*gam[c] + bet[c]);
    }
    *(short8*)(ln1 + lnbase + cc0 + q4*8) = lv;
    *(short8*)(xr + xrbase + cc0 + q4*8) = xv;
  }
}

// ---------------- persistent-B GEMM (K=384): QKV / FC1 ----------------
// B-panel [128][384] resident in LDS (padded stride 408 shorts = 816B ->
// bank-offset period 8, b128 reads at the 8-lane/group floor). 512 threads,
// 8 waves x (64 rows x 128 cols), M-chunk 512. Main loop: A per-lane from
// global (2-step register prefetch), B from LDS, ZERO barriers/DMA/waitcnt.
#define EPI_BIAS 0
#define EPI_PROJ 1
#define EPI_GELU 2
#define EPI_OUT  4

template<int EPI>
__global__ __launch_bounds__(512) void k_gemmB(
    const short* __restrict__ A, const short* __restrict__ B,
    const float* __restrict__ bias, short* __restrict__ out,
    int M, int N, int ntiles)
{
  constexpr int K = 384;
  constexpr int NK = 12;
  __shared__ short smB[128*408];     // 104448 B
  float* E = (float*)smB;            // epilogue overlay [64][132] f32

  int nwg = gridDim.x;
  int bid = bij_swz(blockIdx.x, nwg);
  int nt = bid % ntiles, mt = bid / ntiles;
  int m0 = mt*512, n0 = nt*128;
  int t = threadIdx.x;
  int lane = t & 63, wv = t >> 6;
  int gg = lane >> 4, cc = lane & 15;

  // ---- stage B panel once: 6528 16B-units; unit u -> (row=u/51, slot=u%51)
  // slots 48..50 are pad (loaded from 48B of in-ws slack, never read)
  #pragma unroll
  for (int i = 0; i < 13; i++){
    int u = t + i*512;
    if (i < 12 || t < 384){
      int row = u / 51, s = u - row*51;
      gload_lds16(B + (long)(n0 + row)*K + s*8, smB + u*8);
    }
  }
  asm volatile("s_waitcnt vmcnt(0)" ::: "memory");
  __syncthreads();

  // ---- main loop ----
  const short* Ap = A + (long)(m0 + wv*64 + cc)*K + gg*8;
  const long mstep = 16L*K;

  f32x4 acc[4][8];
  #pragma unroll
  for (int i=0;i<4;i++)
    #pragma unroll
    for (int j=0;j<8;j++) acc[i][j] = (f32x4){0.f,0.f,0.f,0.f};

  short8 a[2][4];
  #pragma unroll
  for (int mi=0;mi<4;mi++) a[0][mi] = *(const short8*)(Ap + mi*mstep);
  #pragma unroll
  for (int mi=0;mi<4;mi++) a[1][mi] = *(const short8*)(Ap + 32 + mi*mstep);

  #pragma unroll
  for (int kt = 0; kt < NK; kt++){
    short8 bfr[8];
    #pragma unroll
    for (int ni=0;ni<8;ni++)
      bfr[ni] = *(const short8*)(smB + (ni*16 + cc)*408 + kt*32 + gg*8);
    #pragma unroll
    for (int mi=0;mi<4;mi++)
      #pragma unroll
      for (int ni=0;ni<8;ni++)
        acc[mi][ni] = __builtin_amdgcn_mfma_f32_16x16x32_bf16(a[kt&1][mi], bfr[ni], acc[mi][ni], 0, 0, 0);
    if (kt + 2 < NK){
      #pragma unroll
      for (int mi=0;mi<4;mi++) a[kt&1][mi] = *(const short8*)(Ap + (kt+2)*32 + mi*mstep);
    }
  }

  // ---- epilogue: 8 passes (one wave's 64x128 at a time) through E ----
  __syncthreads();     // all B reads complete before overlaying E
  for (int pw = 0; pw < 8; pw++){
    if (wv == pw){
      #pragma unroll
      for (int mi=0;mi<4;mi++)
        #pragma unroll
        for (int ni=0;ni<8;ni++)
          #pragma unroll
          for (int r=0;r<4;r++)
            E[(mi*16 + gg*4 + r)*132 + ni*16 + cc] = acc[mi][ni][r];
    }
    __syncthreads();
    #pragma unroll
    for (int jj = 0; jj < 4; jj++){
      int unit = jj*512 + t;
      int crow = unit >> 5, chunk = unit & 31;
      f32x4 v = *(const f32x4*)(E + crow*132 + chunk*4);
      f32x4 bv = *(const f32x4*)(bias + n0 + chunk*4);
      short4v ov;
      #pragma unroll
      for (int j = 0; j < 4; j++){
        float vv = v[j] + bv[j];
        if constexpr (EPI == EPI_GELU) vv = gelu_f(vv);
        ov[j] = f2b(vv);
      }
      *(short4v*)(out + (long)(m0 + pw*64 + crow)*N + n0 + chunk*4) = ov;
    }
    __syncthreads();
  }
}

// ---------------- GEMM (2-phase 128x128, R9/R10-proven): proj / FC2 -------
template<int EPI>
__global__ __launch_bounds__(256) void k_gemm(
    const short* __restrict__ A, const short* __restrict__ B,
    const float* __restrict__ bias, short* __restrict__ out,
    const short* __restrict__ res, int M, int N, int K, int ntiles)
{
  constexpr int ES = (EPI == EPI_OUT) ? 133 : 132;
  __shared__ short sm[20480];    // 40960 B: A 3x8KB @0, B 2x8KB @24KB; epi E overlays
  float* E = (float*)sm;

  int nwg = gridDim.x;
  int orig = blockIdx.x;
  int bid = (orig & 7) * (nwg >> 3) + (orig >> 3);
  int nt = bid % ntiles, mt = bid / ntiles;
  int m0 = mt*128, n0 = nt*128;
  int t = threadIdx.x;
  int lane = t & 63, wv = t >> 6;
  int wm = wv >> 1, wn = wv & 1;
  int gg = lane >> 4, cc = lane & 15;

  int srow = t >> 2;
  int skc = ((t & 3) ^ (srow & 3)) << 3;
  const short* Ab = A + (long)(m0 + srow)*K + skc;
  const short* Bb = B + (long)(n0 + srow)*K + skc;
  long rowstep = 64L*K;

  int goff = (gg << 3) ^ ((cc & 3) << 3);

  f32x4 acc[4][4];
  #pragma unroll
  for (int i=0;i<4;i++)
    #pragma unroll
    for (int j=0;j<4;j++) acc[i][j] = (f32x4){0.f,0.f,0.f,0.f};

  int nk = K >> 5;

  gload_lds16(Ab,           sm + t*8);
  gload_lds16(Ab + rowstep, sm + (t+256)*8);
  gload_lds16(Bb,           sm + 12288 + t*8);
  gload_lds16(Bb + rowstep, sm + 12288 + (t+256)*8);
  gload_lds16(Ab + 32,           sm + 4096 + t*8);
  gload_lds16(Ab + 32 + rowstep, sm + 4096 + (t+256)*8);

  int ac = 0, bc = 0;
  for (int kt = 0; kt < nk; kt++){
    if (kt + 1 < nk) { asm volatile("s_waitcnt vmcnt(2) lgkmcnt(0)" ::: "memory"); }
    else             { asm volatile("s_waitcnt vmcnt(0) lgkmcnt(0)" ::: "memory"); }
    __builtin_amdgcn_s_barrier();
    if (kt + 1 < nk){
      long ko = (long)(kt+1) << 5;
      int bn = bc ^ 1;
      gload_lds16(Bb + ko,           sm + 12288 + bn*4096 + t*8);
      gload_lds16(Bb + ko + rowstep, sm + 12288 + bn*4096 + (t+256)*8);
    }
    if (kt + 2 < nk){
      long ko = (long)(kt+2) << 5;
      int an = ac + 2; if (an >= 3) an -= 3;
      gload_lds16(Ab + ko,           sm + an*4096 + t*8);
      gload_lds16(Ab + ko + rowstep, sm + an*4096 + (t+256)*8);
    }
    const short* Ac = sm + ac*4096;
    const short* Bc = sm + 12288 + bc*4096;
    short8 af[4], bfv[4];
    #pragma unroll
    for (int mi=0;mi<4;mi++) af[mi] = *(const short8*)(Ac + (wm*64 + mi*16 + cc)*32 + goff);
    #pragma unroll
    for (int ni=0;ni<4;ni++) bfv[ni] = *(const short8*)(Bc + (wn*64 + ni*16 + cc)*32 + goff);
    #pragma unroll
    for (int mi=0;mi<4;mi++)
      #pragma unroll
      for (int ni=0;ni<4;ni++)
        acc[mi][ni] = __builtin_amdgcn_mfma_f32_16x16x32_bf16(af[mi], bfv[ni], acc[mi][ni], 0, 0, 0);
    ac = (ac + 1 == 3) ? 0 : ac + 1;
    bc ^= 1;
  }

  if constexpr (EPI == EPI_OUT) {
    float* outf = (float*)out;
    #pragma unroll
    for (int p = 0; p < 2; p++){
      __syncthreads();
      if (wm == p){
        #pragma unroll
        for (int mi=0;mi<4;mi++){
          #pragma unroll
          for (int r=0;r<4;r++){
            float* Er = E + (mi*16 + gg*4 + r)*ES + wn*64 + cc;
            Er[0]  = acc[mi][0][r];
            Er[16] = acc[mi][1][r];
            Er[32] = acc[mi][2][r];
            Er[48] = acc[mi][3][r];
          }
        }
      }
      __syncthreads();
      #pragma unroll
      for (int jj = 0; jj < 8; jj++){
        int unit = jj*256 + t;
        int crow = unit >> 5, chunk = unit & 31;
        int row = m0 + p*64 + crow;
        f32x4 v = *(const f32x4*)(E + crow*ES + chunk*4);
        f32x4 bv = *(const f32x4*)(bias + n0 + chunk*4);
        short4v rv = *(const short4v*)(res + (long)row*N + n0 + chunk*4);
        #pragma unroll
        for (int j = 0; j < 4; j++) v[j] += bv[j] + b2f(rv[j]);
        *(f32x4*)(E + crow*ES + chunk*4) = v;
      }
      __syncthreads();
      #pragma unroll
      for (int jj = 0; jj < 32; jj++){
        int unit = jj*256 + t;
        int c = unit >> 6, rl = unit & 63;
        int token = m0 + p*64 + rl;
        int b = token / HW_;
        int hw = token - b*HW_;
        outf[((long)b*DIM + n0 + c)*HW_ + hw] = E[rl*ES + c];
      }
    }
  } else {
    #pragma unroll
    for (int p = 0; p < 2; p++){
      __syncthreads();
      #pragma unroll
      for (int mh = 0; mh < 2; mh++){
        #pragma unroll
        for (int r = 0; r < 4; r++){
          int crow = wm*32 + mh*16 + gg*4 + r;
          float* Er = E + crow*ES + wn*64 + cc;
          Er[0]  = acc[mh*2 + p][0][r];
          Er[16] = acc[mh*2 + p][1][r];
          Er[32] = acc[mh*2 + p][2][r];
          Er[48] = acc[mh*2 + p][3][r];
        }
      }
      __syncthreads();
      #pragma unroll
      for (int jj = 0; jj < 8; jj++){
        int unit = jj*256 + t;
        int crow = unit >> 5, chunk = unit & 31;
        int rr = crow & 15, mh = (crow >> 4) & 1, wmr = crow >> 5;
        int row = m0 + wmr*64 + (mh*2 + p)*16 + rr;
        int col = n0 + chunk*4;
        f32x4 v = *(const f32x4*)(E + crow*ES + chunk*4);
        f32x4 bv = *(const f32x4*)(bias + col);
        long orow;
        if constexpr (EPI == EPI_PROJ) {
          int b = row / HW_; int rem = row % HW_;
          int wid = rem / 49, idx = rem % 49;
          int hh = (wid >> 3)*7 + idx/7;
          int ww = (wid & 7)*7 + idx%7;
          orow = (long)(b*HW_ + hh*56 + ww)*N;
        } else {
          orow = (long)row*N;
        }
        float vv[4];
        #pragma unroll
        for (int j = 0; j < 4; j++){
          vv[j] = v[j] + bv[j];
          if constexpr (EPI == EPI_GELU) vv[j] = gelu_f(vv[j]);
        }
        if constexpr (EPI == EPI_PROJ){
          short4v rv = *(const short4v*)(res + orow + col);
          #pragma unroll
          for (int j = 0; j < 4; j++) vv[j] += b2f(rv[j]);
        }
        short4v ov;
        #pragma unroll
        for (int j = 0; j < 4; j++) ov[j] = f2b(vv[j]);
        *(short4v*)(out + orow + col) = ov;
      }
    }
  }
}

// ---------------- LN2 (row-wise over token-major bf16) ----------------
__global__ __launch_bounds__(256) void k_ln2(const short* __restrict__ x2,
  const float* __restrict__ gam, const float* __restrict__ bet, short* __restrict__ o)
{
  int t = threadIdx.x, lane = t & 63, wv = t >> 6;
  long row = (long)blockIdx.x*4 + wv;
  const short* xr = x2 + row*DIM;
  short4v a = *(const short4v*)(xr + lane*4);
  short2v b2 = *(const short2v*)(xr + 256 + lane*2);
  float f[6] = {b2f(a[0]),b2f(a[1]),b2f(a[2]),b2f(a[3]),b2f(b2[0]),b2f(b2[1])};
  float s = 0.f, sq = 0.f;
  #pragma unroll
  for (int i=0;i<6;i++){ s += f[i]; sq += f[i]*f[i]; }
  #pragma unroll
  for (int off=1; off<64; off<<=1){ s += __shfl_xor(s, off); sq += __shfl_xor(sq, off); }
  float mu = s*(1.f/DIM);
  float var = sq*(1.f/DIM) - mu*mu;
  float rs = rsqrtf(var + 1e-5f);
  int c0 = lane*4, c1 = 256 + lane*2;
  short4v oa; short2v ob;
  #pragma unroll
  for (int i=0;i<4;i++) oa[i] = f2b((f[i]-mu)*rs*gam[c0+i] + bet[c0+i]);
  #pragma unroll
  for (int j=0;j<2;j++) ob[j] = f2b((f[4+j]-mu)*rs*gam[c1+j] + bet[c1+j]);
  *(short4v*)(o + row*DIM + c0) = oa;
  *(short2v*)(o + row*DIM + c1) = ob;
}

// ---------------- window attention (barrier-free, wave-private LDS) -------
__global__ __launch_bounds__(256) void k_attn(const short* __restrict__ qkv, short* __restrict__ o)
{
  __shared__ short lds[4*7424];
  int t = threadIdx.x;
  int lane = t & 63, wv = t >> 6;
  int w = blockIdx.x;
  int h = wv + (int)blockIdx.y*4;
  short* Qs = lds + wv*7424;   // [64][40]
  short* Ks = Qs + 2560;       // [64][40]
  short* Vt = Ks + 2560;       // [32][72]
  short* Pl = Qs;              // [64][72] overlaps Q+K (wave-private)
  int g = lane >> 4, c = lane & 15;
  int nrow = lane >> 2;
  int dc = (lane & 3) * 8;
  const float scale = 0.17677669529663687f;

  long base = (long)w*49*1152 + h*32;
  #pragma unroll
  for (int it = 0; it < 4; it++){
    int n = it*16 + nrow;
    short8 vq = {0,0,0,0,0,0,0,0};
    short8 vk = vq, vvv = vq;
    if (n < 49){
      vq  = *(const short8*)(qkv + base + (long)n*1152 + dc);
      vk  = *(const short8*)(qkv + base + (long)n*1152 + 384 + dc);
      vvv = *(const short8*)(qkv + base + (long)n*1152 + 768 + dc);
    }
    *(short8*)(Qs + n*40 + dc) = vq;
    *(short8*)(Ks + n*40 + dc) = vk;
    #pragma unroll
    for (int u = 0; u < 8; u++) Vt[(dc+u)*72 + n] = vvv[u];
  }
  asm volatile("s_waitcnt lgkmcnt(0)" ::: "memory");
  __builtin_amdgcn_sched_barrier(0);

  f32x4 sacc[4][4];
  #pragma unroll
  for (int i=0;i<4;i++)
    #pragma unroll
    for (int j=0;j<4;j++) sacc[i][j] = (f32x4){0.f,0.f,0.f,0.f};
  short8 kf[4];
  #pragma unroll
  for (int ni=0;ni<4;ni++) kf[ni] = *(const short8*)(Ks + (ni*16 + c)*40 + g*8);
  #pragma unroll
  for (int mi=0;mi<4;mi++){
    short8 a = *(const short8*)(Qs + (mi*16 + c)*40 + g*8);
    #pragma unroll
    for (int ni=0;ni<4;ni++)
      sacc[mi][ni] = __builtin_amdgcn_mfma_f32_16x16x32_bf16(a, kf[ni], sacc[mi][ni], 0, 0, 0);
  }
  #pragma unroll
  for (int mi=0;mi<4;mi++){
    #pragma unroll
    for (int r=0;r<4;r++){
      float v0 = sacc[mi][0][r]*scale;
      float v1 = sacc[mi][1][r]*scale;
      float v2 = sacc[mi][2][r]*scale;
      float v3 = (c >= 1) ? -1e30f : sacc[mi][3][r]*scale;
      float mx = fmaxf(fmaxf(v0,v1), fmaxf(v2,v3));
      #pragma unroll
      for (int off=1; off<16; off<<=1) mx = fmaxf(mx, __shfl_xor(mx, off));
      float e0 = __expf(v0-mx), e1 = __expf(v1-mx), e2 = __expf(v2-mx), e3 = __expf(v3-mx);
      float sm = e0+e1+e2+e3;
      #pragma unroll
      for (int off=1; off<16; off<<=1) sm += __shfl_xor(sm, off);
      float inv = 1.f/sm;
      int prow = mi*16 + g*4 + r;
      Pl[prow*72 +      c] = f2b(e0*inv);
      Pl[prow*72 + 16 + c] = f2b(e1*inv);
      Pl[prow*72 + 32 + c] = f2b(e2*inv);
      Pl[prow*72 + 48 + c] = f2b(e3*inv);
    }
  }
  asm volatile("s_waitcnt lgkmcnt(0)" ::: "memory");
  __builtin_amdgcn_sched_barrier(0);

  f32x4 oacc[4][2];
  #pragma unroll
  for (int i=0;i<4;i++){ oacc[i][0] = (f32x4){0.f,0.f,0.f,0.f}; oacc[i][1] = oacc[i][0]; }
  #pragma unroll
  for (int ks=0; ks<2; ks++){
    short8 bb0 = *(const short8*)(Vt + (c)*72      + ks*32 + g*8);
    short8 bb1 = *(const short8*)(Vt + (16 + c)*72 + ks*32 + g*8);
    #pragma unroll
    for (int mi=0;mi<4;mi++){
      short8 aa = *(const short8*)(Pl + (mi*16 + c)*72 + ks*32 + g*8);
      oacc[mi][0] = __builtin_amdgcn_mfma_f32_16x16x32_bf16(aa, bb0, oacc[mi][0], 0, 0, 0);
      oacc[mi][1] = __builtin_amdgcn_mfma_f32_16x16x32_bf16(aa, bb1, oacc[mi][1], 0, 0, 0);
    }
  }
  #pragma unroll
  for (int mi=0;mi<4;mi++){
    #pragma unroll
    for (int r=0;r<4;r++){
      int row = mi*16 + g*4 + r;
      if (row < 49){
        long ob = ((long)w*49 + row)*384 + h*32;
        o[ob + c]      = f2b(oacc[mi][0][r]);
        o[ob + 16 + c] = f2b(oacc[mi][1][r]);
      }
    }
  }
}

extern "C" void kernel_launch(void* const* d_in, const int* in_sizes, int n_in,
                              void* d_out, int out_size, void* d_ws, size_t ws_size,
                              hipStream_t stream) {
  (void)in_sizes; (void)n_in; (void)out_size; (void)ws_size;
  const float* x      = (const float*)d_in[0];
  const float* ln1_g  = (const float*)d_in[1];
  const float* ln1_b  = (const float*)d_in[2];
  const float* qkv_w  = (const float*)d_in[3];
  const float* qkv_b  = (const float*)d_in[4];
  const float* proj_w = (const float*)d_in[5];
  const float* proj_b = (const float*)d_in[6];
  const float* ln2_g  = (const float*)d_in[7];
  const float* ln2_b  = (const float*)d_in[8];
  const float* fc1_w  = (const float*)d_in[9];
  const float* fc1_b  = (const float*)d_in[10];
  const float* fc2_w  = (const float*)d_in[11];
  const float* fc2_b  = (const float*)d_in[12];

  char* ws = (char*)d_ws;
  short* buf1 = (short*)(ws);                 // qkv [T,1152] / h1 [T,1024]
  short* buf2 = (short*)(ws + 231211008L);    // ln1 (window-major) / ln2 (raster)
  short* buf3 = (short*)(ws + 308281344L);    // attn out (window-major)
  short* buf4 = (short*)(ws + 385351680L);    // x2 residual (raster)
  short* buf5 = (short*)(ws + 462422016L);    // x raster copy bf16
  short* wq = (short*)(ws + 539492352L);
  short* wp = wq + 442368;
  short* w1 = wp + 147456;
  short* w2 = w1 + 393216;

  k_cvt4<<<dim3(1728), dim3(256), 0, stream>>>(qkv_w, proj_w, fc1_w, fc2_w,
                                               wq, wp, w1, w2);

  k_ln1<<<dim3(1568), dim3(256), 0, stream>>>(x, ln1_g, ln1_b, buf2, buf5);

  // QKV: persistent-B (196 M-chunks x 9 N-tiles)
  k_gemmB<EPI_BIAS><<<dim3(196*9), dim3(512), 0, stream>>>(buf2, wq, qkv_b, buf1,
                                                           TOKENS, 1152, 9);
  k_attn<<<dim3(NWIN, 3), dim3(256), 0, stream>>>(buf1, buf3);

  // proj + residual + window->raster permute (writes x2 = buf4)
  k_gemm<EPI_PROJ><<<dim3(784*3), dim3(256), 0, stream>>>(buf3, wp, proj_b, buf4, buf5,
                                                          TOKENS, 384, 384, 3);
  k_ln2<<<dim3(TOKENS/4), dim3(256), 0, stream>>>(buf4, ln2_g, ln2_b, buf2);

  // FC1: persistent-B (196 M-chunks x 8 N-tiles)
  k_gemmB<EPI_GELU><<<dim3(196*8), dim3(512), 0, stream>>>(buf2, w1, fc1_b, buf1,
                                                           TOKENS, 1024, 8);
  // FC2 + residual + NCHW f32 output
  k_gemm<EPI_OUT><<<dim3(784*3), dim3(256), 0, stream>>>(buf1, w2, fc2_b, (short*)d_out, buf4,
                                                         TOKENS, 384, 1024, 3);
}

// Round 14
// 714.913 us; speedup vs baseline: 1.1442x; 1.1442x over previous
//
#include <hip/hip_runtime.h>
#include <cstdint>
#include <cmath>

#define DIM 384
#define HEADS 12
#define TOKENS 100352   // 32*56*56
#define HW_ 3136        // 56*56
#define NWIN 2048       // 32*8*8

typedef __attribute__((ext_vector_type(8))) short short8;
typedef __attribute__((ext_vector_type(4))) short short4v;
typedef __attribute__((ext_vector_type(2))) short short2v;
typedef __attribute__((ext_vector_type(4))) float f32x4;

#define AS1 __attribute__((address_space(1)))
#define AS3 __attribute__((address_space(3)))

__device__ __forceinline__ short f2b(float f){
  unsigned u = __builtin_bit_cast(unsigned, f);
  u += 0x7FFFu + ((u >> 16) & 1u);
  return (short)(u >> 16);
}
__device__ __forceinline__ float b2f(short h){
  unsigned u = ((unsigned)(unsigned short)h) << 16;
  return __builtin_bit_cast(float, u);
}

__device__ __forceinline__ void gload_lds16(const short* g, short* l){
  __builtin_amdgcn_global_load_lds((AS1 void*)(g), (AS3 void*)(l), 16, 0, 0);
}

// exact GELU via A&S 7.1.26 rational erf (|eps| <= 1.5e-7)
__device__ __forceinline__ float gelu_f(float v){
  float z  = v * 0.70710678118654752f;
  float az = fabsf(z);
  float t  = __builtin_amdgcn_rcpf(1.f + 0.3275911f*az);
  float poly = t*(0.254829592f + t*(-0.284496736f + t*(1.421413741f +
               t*(-1.453152027f + t*1.061405429f))));
  float e  = __expf(-z*z);
  float er = copysignf(1.f - poly*e, z);
  return 0.5f * v * (1.f + er);
}

// ---------------- all 4 weight tensors f32 -> bf16, one launch ----------------
// segments: qkv_w 442368 | proj_w 147456 | fc1_w 393216 | fc2_w 393216
__global__ __launch_bounds__(256) void k_cvt4(
    const float* __restrict__ s0, const float* __restrict__ s1,
    const float* __restrict__ s2, const float* __restrict__ s3,
    short* __restrict__ d0, short* __restrict__ d1,
    short* __restrict__ d2, short* __restrict__ d3)
{
  int i = blockIdx.x*256 + threadIdx.x;
  if (i < 442368) d0[i] = f2b(s0[i]);
  if (i < 147456) d1[i] = f2b(s1[i]);
  if (i < 393216){ d2[i] = f2b(s2[i]); d3[i] = f2b(s3[i]); }
}

// ---------------- LN1 + NCHW->token transpose (single global read) --------
__global__ __launch_bounds__(256) void k_ln1(const float* __restrict__ x,
    const float* __restrict__ gam, const float* __restrict__ bet,
    short* __restrict__ ln1, short* __restrict__ xr)
{
  __shared__ float red0[256];
  __shared__ float red1[256];
  __shared__ float mus[64], rss[64];
  __shared__ short xfull[64*388];
  int t = threadIdx.x;
  int blk = blockIdx.x;
  int b = blk / 49;
  int hw0 = (blk % 49) * 64;
  int p = t & 63, cq = t >> 6;
  const float* xb = x + (long)b*DIM*HW_ + hw0 + p;
  float s = 0.f, sq = 0.f;
  for (int i = 0; i < 96; i++){
    int c = i*4 + cq;
    float v = xb[(long)c*HW_];
    s += v; sq += v*v;
    xfull[p*388 + c] = f2b(v);
  }
  red0[t] = s; red1[t] = sq;
  __syncthreads();
  if (t < 64){
    float ts = red0[t] + red0[t+64] + red0[t+128] + red0[t+192];
    float tq = red1[t] + red1[t+64] + red1[t+128] + red1[t+192];
    float mu = ts * (1.f/DIM);
    float var = tq * (1.f/DIM) - mu*mu;
    mus[t] = mu;
    rss[t] = rsqrtf(var + 1e-5f);
  }
  __syncthreads();
  int p2 = t >> 2, q4 = t & 3;
  float mu = mus[p2], rs = rss[p2];
  int hwp2 = hw0 + p2;
  int h2 = hwp2 / 56, w2 = hwp2 % 56;
  int wt2 = ((b*8 + h2/7)*8 + w2/7)*49 + (h2%7)*7 + (w2%7);
  long lnbase = (long)wt2*DIM;
  long xrbase = (long)(b*HW_ + hwp2)*DIM;
  #pragma unroll
  for (int cc0 = 0; cc0 < DIM; cc0 += 32){
    short8 xv = *(const short8*)(xfull + p2*388 + cc0 + q4*8);
    short8 lv;
    #pragma unroll
    for (int u = 0; u < 8; u++){
      int c = cc0 + q4*8 + u;
      float v = b2f(xv[u]);
      lv[u] = f2b((v - mu)*rs*gam[c] + bet[c]);
    }
    *(short8*)(ln1 + lnbase + cc0 + q4*8) = lv;
    *(short8*)(xr + xrbase + cc0 + q4*8) = xv;
  }
}

// ---------------- GEMM (2-phase 128x128, R9/R10-proven) ----------------
#define EPI_BIAS 0
#define EPI_PROJ 1
#define EPI_GELU 2
#define EPI_OUT  4

template<int EPI>
__global__ __launch_bounds__(256) void k_gemm(
    const short* __restrict__ A, const short* __restrict__ B,
    const float* __restrict__ bias, short* __restrict__ out,
    const short* __restrict__ res, int M, int N, int K, int ntiles)
{
  constexpr int ES = (EPI == EPI_OUT) ? 133 : 132;
  __shared__ short sm[20480];    // 40960 B: A 3x8KB @0, B 2x8KB @24KB; epi E overlays
  float* E = (float*)sm;

  int nwg = gridDim.x;
  int orig = blockIdx.x;
  int bid = (orig & 7) * (nwg >> 3) + (orig >> 3);
  int nt = bid % ntiles, mt = bid / ntiles;
  int m0 = mt*128, n0 = nt*128;
  int t = threadIdx.x;
  int lane = t & 63, wv = t >> 6;
  int wm = wv >> 1, wn = wv & 1;
  int gg = lane >> 4, cc = lane & 15;

  int srow = t >> 2;
  int skc = ((t & 3) ^ (srow & 3)) << 3;
  const short* Ab = A + (long)(m0 + srow)*K + skc;
  const short* Bb = B + (long)(n0 + srow)*K + skc;
  long rowstep = 64L*K;

  int goff = (gg << 3) ^ ((cc & 3) << 3);

  f32x4 acc[4][4];
  #pragma unroll
  for (int i=0;i<4;i++)
    #pragma unroll
    for (int j=0;j<4;j++) acc[i][j] = (f32x4){0.f,0.f,0.f,0.f};

  int nk = K >> 5;

  gload_lds16(Ab,           sm + t*8);
  gload_lds16(Ab + rowstep, sm + (t+256)*8);
  gload_lds16(Bb,           sm + 12288 + t*8);
  gload_lds16(Bb + rowstep, sm + 12288 + (t+256)*8);
  gload_lds16(Ab + 32,           sm + 4096 + t*8);
  gload_lds16(Ab + 32 + rowstep, sm + 4096 + (t+256)*8);

  int ac = 0, bc = 0;
  for (int kt = 0; kt < nk; kt++){
    if (kt + 1 < nk) { asm volatile("s_waitcnt vmcnt(2) lgkmcnt(0)" ::: "memory"); }
    else             { asm volatile("s_waitcnt vmcnt(0) lgkmcnt(0)" ::: "memory"); }
    __builtin_amdgcn_s_barrier();
    if (kt + 1 < nk){
      long ko = (long)(kt+1) << 5;
      int bn = bc ^ 1;
      gload_lds16(Bb + ko,           sm + 12288 + bn*4096 + t*8);
      gload_lds16(Bb + ko + rowstep, sm + 12288 + bn*4096 + (t+256)*8);
    }
    if (kt + 2 < nk){
      long ko = (long)(kt+2) << 5;
      int an = ac + 2; if (an >= 3) an -= 3;
      gload_lds16(Ab + ko,           sm + an*4096 + t*8);
      gload_lds16(Ab + ko + rowstep, sm + an*4096 + (t+256)*8);
    }
    const short* Ac = sm + ac*4096;
    const short* Bc = sm + 12288 + bc*4096;
    short8 af[4], bfv[4];
    #pragma unroll
    for (int mi=0;mi<4;mi++) af[mi] = *(const short8*)(Ac + (wm*64 + mi*16 + cc)*32 + goff);
    #pragma unroll
    for (int ni=0;ni<4;ni++) bfv[ni] = *(const short8*)(Bc + (wn*64 + ni*16 + cc)*32 + goff);
    #pragma unroll
    for (int mi=0;mi<4;mi++)
      #pragma unroll
      for (int ni=0;ni<4;ni++)
        acc[mi][ni] = __builtin_amdgcn_mfma_f32_16x16x32_bf16(af[mi], bfv[ni], acc[mi][ni], 0, 0, 0);
    ac = (ac + 1 == 3) ? 0 : ac + 1;
    bc ^= 1;
  }

  if constexpr (EPI == EPI_OUT) {
    float* outf = (float*)out;
    #pragma unroll
    for (int p = 0; p < 2; p++){
      __syncthreads();
      if (wm == p){
        #pragma unroll
        for (int mi=0;mi<4;mi++){
          #pragma unroll
          for (int r=0;r<4;r++){
            float* Er = E + (mi*16 + gg*4 + r)*ES + wn*64 + cc;
            Er[0]  = acc[mi][0][r];
            Er[16] = acc[mi][1][r];
            Er[32] = acc[mi][2][r];
            Er[48] = acc[mi][3][r];
          }
        }
      }
      __syncthreads();
      #pragma unroll
      for (int jj = 0; jj < 8; jj++){
        int unit = jj*256 + t;
        int crow = unit >> 5, chunk = unit & 31;
        int row = m0 + p*64 + crow;
        f32x4 v = *(const f32x4*)(E + crow*ES + chunk*4);
        f32x4 bv = *(const f32x4*)(bias + n0 + chunk*4);
        short4v rv = *(const short4v*)(res + (long)row*N + n0 + chunk*4);
        #pragma unroll
        for (int j = 0; j < 4; j++) v[j] += bv[j] + b2f(rv[j]);
        *(f32x4*)(E + crow*ES + chunk*4) = v;
      }
      __syncthreads();
      #pragma unroll
      for (int jj = 0; jj < 32; jj++){
        int unit = jj*256 + t;
        int c = unit >> 6, rl = unit & 63;
        int token = m0 + p*64 + rl;
        int b = token / HW_;
        int hw = token - b*HW_;
        outf[((long)b*DIM + n0 + c)*HW_ + hw] = E[rl*ES + c];
      }
    }
  } else {
    #pragma unroll
    for (int p = 0; p < 2; p++){
      __syncthreads();
      #pragma unroll
      for (int mh = 0; mh < 2; mh++){
        #pragma unroll
        for (int r = 0; r < 4; r++){
          int crow = wm*32 + mh*16 + gg*4 + r;
          float* Er = E + crow*ES + wn*64 + cc;
          Er[0]  = acc[mh*2 + p][0][r];
          Er[16] = acc[mh*2 + p][1][r];
          Er[32] = acc[mh*2 + p][2][r];
          Er[48] = acc[mh*2 + p][3][r];
        }
      }
      __syncthreads();
      #pragma unroll
      for (int jj = 0; jj < 8; jj++){
        int unit = jj*256 + t;
        int crow = unit >> 5, chunk = unit & 31;
        int rr = crow & 15, mh = (crow >> 4) & 1, wmr = crow >> 5;
        int row = m0 + wmr*64 + (mh*2 + p)*16 + rr;
        int col = n0 + chunk*4;
        f32x4 v = *(const f32x4*)(E + crow*ES + chunk*4);
        f32x4 bv = *(const f32x4*)(bias + col);
        long orow;
        if constexpr (EPI == EPI_PROJ) {
          int b = row / HW_; int rem = row % HW_;
          int wid = rem / 49, idx = rem % 49;
          int hh = (wid >> 3)*7 + idx/7;
          int ww = (wid & 7)*7 + idx%7;
          orow = (long)(b*HW_ + hh*56 + ww)*N;
        } else {
          orow = (long)row*N;
        }
        float vv[4];
        #pragma unroll
        for (int j = 0; j < 4; j++){
          vv[j] = v[j] + bv[j];
          if constexpr (EPI == EPI_GELU) vv[j] = gelu_f(vv[j]);
        }
        if constexpr (EPI == EPI_PROJ){
          short4v rv = *(const short4v*)(res + orow + col);
          #pragma unroll
          for (int j = 0; j < 4; j++) vv[j] += b2f(rv[j]);
        }
        short4v ov;
        #pragma unroll
        for (int j = 0; j < 4; j++) ov[j] = f2b(vv[j]);
        *(short4v*)(out + orow + col) = ov;
      }
    }
  }
}

// ---------------- LN2 (row-wise over token-major bf16) ----------------
__global__ __launch_bounds__(256) void k_ln2(const short* __restrict__ x2,
  const float* __restrict__ gam, const float* __restrict__ bet, short* __restrict__ o)
{
  int t = threadIdx.x, lane = t & 63, wv = t >> 6;
  long row = (long)blockIdx.x*4 + wv;
  const short* xr = x2 + row*DIM;
  short4v a = *(const short4v*)(xr + lane*4);
  short2v b2 = *(const short2v*)(xr + 256 + lane*2);
  float f[6] = {b2f(a[0]),b2f(a[1]),b2f(a[2]),b2f(a[3]),b2f(b2[0]),b2f(b2[1])};
  float s = 0.f, sq = 0.f;
  #pragma unroll
  for (int i=0;i<6;i++){ s += f[i]; sq += f[i]*f[i]; }
  #pragma unroll
  for (int off=1; off<64; off<<=1){ s += __shfl_xor(s, off); sq += __shfl_xor(sq, off); }
  float mu = s*(1.f/DIM);
  float var = sq*(1.f/DIM) - mu*mu;
  float rs = rsqrtf(var + 1e-5f);
  int c0 = lane*4, c1 = 256 + lane*2;
  short4v oa; short2v ob;
  #pragma unroll
  for (int i=0;i<4;i++) oa[i] = f2b((f[i]-mu)*rs*gam[c0+i] + bet[c0+i]);
  #pragma unroll
  for (int j=0;j<2;j++) ob[j] = f2b((f[4+j]-mu)*rs*gam[c1+j] + bet[c1+j]);
  *(short4v*)(o + row*DIM + c0) = oa;
  *(short2v*)(o + row*DIM + c1) = ob;
}

// ---------------- window attention (barrier-free, wave-private LDS) -------
__global__ __launch_bounds__(256) void k_attn(const short* __restrict__ qkv, short* __restrict__ o)
{
  __shared__ short lds[4*7424];
  int t = threadIdx.x;
  int lane = t & 63, wv = t >> 6;
  int w = blockIdx.x;
  int h = wv + (int)blockIdx.y*4;
  short* Qs = lds + wv*7424;   // [64][40]
  short* Ks = Qs + 2560;       // [64][40]
  short* Vt = Ks + 2560;       // [32][72]
  short* Pl = Qs;              // [64][72] overlaps Q+K (wave-private)
  int g = lane >> 4, c = lane & 15;
  int nrow = lane >> 2;
  int dc = (lane & 3) * 8;
  const float scale = 0.17677669529663687f;

  long base = (long)w*49*1152 + h*32;
  #pragma unroll
  for (int it = 0; it < 4; it++){
    int n = it*16 + nrow;
    short8 vq = {0,0,0,0,0,0,0,0};
    short8 vk = vq, vvv = vq;
    if (n < 49){
      vq  = *(const short8*)(qkv + base + (long)n*1152 + dc);
      vk  = *(const short8*)(qkv + base + (long)n*1152 + 384 + dc);
      vvv = *(const short8*)(qkv + base + (long)n*1152 + 768 + dc);
    }
    *(short8*)(Qs + n*40 + dc) = vq;
    *(short8*)(Ks + n*40 + dc) = vk;
    #pragma unroll
    for (int u = 0; u < 8; u++) Vt[(dc+u)*72 + n] = vvv[u];
  }
  asm volatile("s_waitcnt lgkmcnt(0)" ::: "memory");
  __builtin_amdgcn_sched_barrier(0);

  f32x4 sacc[4][4];
  #pragma unroll
  for (int i=0;i<4;i++)
    #pragma unroll
    for (int j=0;j<4;j++) sacc[i][j] = (f32x4){0.f,0.f,0.f,0.f};
  short8 kf[4];
  #pragma unroll
  for (int ni=0;ni<4;ni++) kf[ni] = *(const short8*)(Ks + (ni*16 + c)*40 + g*8);
  #pragma unroll
  for (int mi=0;mi<4;mi++){
    short8 a = *(const short8*)(Qs + (mi*16 + c)*40 + g*8);
    #pragma unroll
    for (int ni=0;ni<4;ni++)
      sacc[mi][ni] = __builtin_amdgcn_mfma_f32_16x16x32_bf16(a, kf[ni], sacc[mi][ni], 0, 0, 0);
  }
  #pragma unroll
  for (int mi=0;mi<4;mi++){
    #pragma unroll
    for (int r=0;r<4;r++){
      float v0 = sacc[mi][0][r]*scale;
      float v1 = sacc[mi][1][r]*scale;
      float v2 = sacc[mi][2][r]*scale;
      float v3 = (c >= 1) ? -1e30f : sacc[mi][3][r]*scale;
      float mx = fmaxf(fmaxf(v0,v1), fmaxf(v2,v3));
      #pragma unroll
      for (int off=1; off<16; off<<=1) mx = fmaxf(mx, __shfl_xor(mx, off));
      float e0 = __expf(v0-mx), e1 = __expf(v1-mx), e2 = __expf(v2-mx), e3 = __expf(v3-mx);
      float sm = e0+e1+e2+e3;
      #pragma unroll
      for (int off=1; off<16; off<<=1) sm += __shfl_xor(sm, off);
      float inv = 1.f/sm;
      int prow = mi*16 + g*4 + r;
      Pl[prow*72 +      c] = f2b(e0*inv);
      Pl[prow*72 + 16 + c] = f2b(e1*inv);
      Pl[prow*72 + 32 + c] = f2b(e2*inv);
      Pl[prow*72 + 48 + c] = f2b(e3*inv);
    }
  }
  asm volatile("s_waitcnt lgkmcnt(0)" ::: "memory");
  __builtin_amdgcn_sched_barrier(0);

  f32x4 oacc[4][2];
  #pragma unroll
  for (int i=0;i<4;i++){ oacc[i][0] = (f32x4){0.f,0.f,0.f,0.f}; oacc[i][1] = oacc[i][0]; }
  #pragma unroll
  for (int ks=0; ks<2; ks++){
    short8 bb0 = *(const short8*)(Vt + (c)*72      + ks*32 + g*8);
    short8 bb1 = *(const short8*)(Vt + (16 + c)*72 + ks*32 + g*8);
    #pragma unroll
    for (int mi=0;mi<4;mi++){
      short8 aa = *(const short8*)(Pl + (mi*16 + c)*72 + ks*32 + g*8);
      oacc[mi][0] = __builtin_amdgcn_mfma_f32_16x16x32_bf16(aa, bb0, oacc[mi][0], 0, 0, 0);
      oacc[mi][1] = __builtin_amdgcn_mfma_f32_16x16x32_bf16(aa, bb1, oacc[mi][1], 0, 0, 0);
    }
  }
  #pragma unroll
  for (int mi=0;mi<4;mi++){
    #pragma unroll
    for (int r=0;r<4;r++){
      int row = mi*16 + g*4 + r;
      if (row < 49){
        long ob = ((long)w*49 + row)*384 + h*32;
        o[ob + c]      = f2b(oacc[mi][0][r]);
        o[ob + 16 + c] = f2b(oacc[mi][1][r]);
      }
    }
  }
}

extern "C" void kernel_launch(void* const* d_in, const int* in_sizes, int n_in,
                              void* d_out, int out_size, void* d_ws, size_t ws_size,
                              hipStream_t stream) {
  (void)in_sizes; (void)n_in; (void)out_size; (void)ws_size;
  const float* x      = (const float*)d_in[0];
  const float* ln1_g  = (const float*)d_in[1];
  const float* ln1_b  = (const float*)d_in[2];
  const float* qkv_w  = (const float*)d_in[3];
  const float* qkv_b  = (const float*)d_in[4];
  const float* proj_w = (const float*)d_in[5];
  const float* proj_b = (const float*)d_in[6];
  const float* ln2_g  = (const float*)d_in[7];
  const float* ln2_b  = (const float*)d_in[8];
  const float* fc1_w  = (const float*)d_in[9];
  const float* fc1_b  = (const float*)d_in[10];
  const float* fc2_w  = (const float*)d_in[11];
  const float* fc2_b  = (const float*)d_in[12];

  char* ws = (char*)d_ws;
  short* buf1 = (short*)(ws);                 // qkv [T,1152] / h1 [T,1024]
  short* buf2 = (short*)(ws + 231211008L);    // ln1 (window-major) / ln2 (raster)
  short* buf3 = (short*)(ws + 308281344L);    // attn out (window-major)
  short* buf4 = (short*)(ws + 385351680L);    // x2 residual (raster)
  short* buf5 = (short*)(ws + 462422016L);    // x raster copy bf16
  short* wq = (short*)(ws + 539492352L);
  short* wp = wq + 442368;
  short* w1 = wp + 147456;
  short* w2 = w1 + 393216;

  k_cvt4<<<dim3(1728), dim3(256), 0, stream>>>(qkv_w, proj_w, fc1_w, fc2_w,
                                               wq, wp, w1, w2);

  k_ln1<<<dim3(1568), dim3(256), 0, stream>>>(x, ln1_g, ln1_b, buf2, buf5);

  k_gemm<EPI_BIAS><<<dim3(784*9), dim3(256), 0, stream>>>(buf2, wq, qkv_b, buf1, nullptr,
                                                          TOKENS, 1152, 384, 9);
  k_attn<<<dim3(NWIN, 3), dim3(256), 0, stream>>>(buf1, buf3);

  // proj + residual + window->raster permute (writes x2 = buf4)
  k_gemm<EPI_PROJ><<<dim3(784*3), dim3(256), 0, stream>>>(buf3, wp, proj_b, buf4, buf5,
                                                          TOKENS, 384, 384, 3);
  k_ln2<<<dim3(TOKENS/4), dim3(256), 0, stream>>>(buf4, ln2_g, ln2_b, buf2);

  k_gemm<EPI_GELU><<<dim3(784*8), dim3(256), 0, stream>>>(buf2, w1, fc1_b, buf1, nullptr,
                                                          TOKENS, 1024, 384, 8);
  // FC2 + residual + NCHW f32 output
  k_gemm<EPI_OUT><<<dim3(784*3), dim3(256), 0, stream>>>(buf1, w2, fc2_b, (short*)d_out, buf4,
                                                         TOKENS, 384, 1024, 3);
}